// Round 4
// baseline (1311.396 us; speedup 1.0000x reference)
//
#include <hip/hip_runtime.h>
#include <hip/hip_bf16.h>
#include <math.h>

#define NB 32768
#define DIM 512
#define KF 8
#define FEAT 8192
#define BM 128
#define BK 64
#define NSTEP (FEAT / BK)   // 128

typedef __attribute__((ext_vector_type(8))) short bf16x8;
typedef __attribute__((ext_vector_type(4))) float f32x4;

static __device__ __forceinline__ short f2bf(float f) {
    union { __hip_bfloat16 h; short s; } u;
    u.h = __float2bfloat16(f);
    return u.s;
}

static __device__ __forceinline__ void stage16(const unsigned short* g, unsigned short* l) {
    __builtin_amdgcn_global_load_lds((const __attribute__((address_space(1))) unsigned int*)g,
                                     (__attribute__((address_space(3))) unsigned int*)l, 16, 0, 0);
}
static __device__ __forceinline__ void stage4(const float* g, float* l) {
    __builtin_amdgcn_global_load_lds((const __attribute__((address_space(1))) unsigned int*)g,
                                     (__attribute__((address_space(3))) unsigned int*)l, 4, 0, 0);
}

// Feature fragment for one x: v[j] = halfSel ? cos(j*x) : sin(j*x), j=0..7 (branchless select).
static __device__ __forceinline__ bf16x8 make_frag(float x, int halfSel, short e0) {
    float s1, c1;
    __sincosf(x, &s1, &c1);
    bf16x8 v;
    v[0] = e0;                       // sin(0)=0 / cos(0)=1
    v[1] = f2bf(halfSel ? c1 : s1);
    float sk = s1, ck = c1;
#pragma unroll
    for (int k = 2; k < KF; ++k) {
        float sn = sk * c1 + ck * s1;
        float cn = ck * c1 - sk * s1;
        sk = sn; ck = cn;
        v[k] = f2bf(halfSel ? cn : sn);
    }
    return v;
}

// ---------------- pack A,B (fp32 [512][512][8]) -> Wt bf16 [512][8192] ----------------
__global__ void pack_w(const float* __restrict__ A, const float* __restrict__ B,
                       unsigned short* __restrict__ Wt) {
    int idx = blockIdx.x * 256 + threadIdx.x;
    int o = idx >> 9, i = idx & 511;
    const float* a = A + ((size_t)o * DIM + i) * KF;
    const float* b = B + ((size_t)o * DIM + i) * KF;
    bf16x8 v0, v1;
#pragma unroll
    for (int j = 0; j < 8; ++j) {
        v0[j] = f2bf(a[j]);
        v1[j] = f2bf(b[j]);
    }
    unsigned short* dst = Wt + (size_t)o * FEAT + i * 16;
    *(bf16x8*)dst = v0;
    *(bf16x8*)(dst + 8) = v1;
}

// ---------------- layer 0: in=1 -> out=512 ----------------
__global__ void layer0(const float* __restrict__ x, const float* __restrict__ A0,
                       const float* __restrict__ B0, float* __restrict__ Y) {
    int gid = blockIdx.x * 256 + threadIdx.x;
    int b = gid >> 9, o = gid & 511;
    float xv = x[b];
    float s1, c1;
    __sincosf(xv, &s1, &c1);
    const float* a = A0 + o * KF;
    const float* bb = B0 + o * KF;
    float acc = bb[0];
    float sk = 0.f, ck = 1.f;
#pragma unroll
    for (int k = 1; k < KF; ++k) {
        float sn = sk * c1 + ck * s1;
        float cn = ck * c1 - sk * s1;
        sk = sn; ck = cn;
        acc += a[k] * sk + bb[k] * ck;
    }
    Y[gid] = acc;
}

// ---------------- fused feature+GEMM ----------------
// A-fragments computed per-lane in registers (no LDS for A). B via global_load_lds,
// double-buffered, XOR-swizzled. x fed through 2x2KB LDS ping-pong staged 2 steps ahead.
__global__ __launch_bounds__(512, 2) void fkan_gemm(const float* __restrict__ X,
                                                    const unsigned short* __restrict__ Wt,
                                                    float* __restrict__ Y) {
    __shared__ unsigned short Blds[2][DIM * BK];  // 2 x 64 KB
    __shared__ float Xlds[2][BM * 4];             // 2 x 2 KB
    const int tid = threadIdx.x;
    const int lane = tid & 63, wave = tid >> 6;
    const int wr = wave >> 2, wc = wave & 3;      // 2x4 wave grid, wave tile 64x128
    const int l15 = lane & 15, l4 = lane >> 4;
    const int bm0 = blockIdx.x * BM;

    const int i0 = l4 >> 1;                       // which input (mod 2) this lane consumes
    const int halfSel = l4 & 1;                   // 0 = sin-half, 1 = cos-half
    const short e0 = halfSel ? (short)0x3F80 : (short)0;

    // B staging: LDS slot u=(row,c) holds global unit (c ^ (row&7)) -> pre-swizzled src.
    int srcoff[8];
#pragma unroll
    for (int q = 0; q < 8; ++q) {
        int u = wave * 512 + q * 64 + lane;
        int row = u >> 3, c = u & 7;
        srcoff[q] = row * FEAT + ((c ^ (row & 7)) * 8);
    }

    // X staging: one float per thread per step; dest base wave-uniform (lane lands at +lane*4)
    const int xrow = tid >> 2, xi = tid & 3;
    const float* xg = X + (size_t)(bm0 + xrow) * DIM + xi;

    f32x4 acc[4][8];
#pragma unroll
    for (int m = 0; m < 4; ++m)
#pragma unroll
        for (int n = 0; n < 8; ++n) acc[m][n] = (f32x4)0.f;

    bf16x8 afr[4][2];   // current-step A fragments [m][kk]

    // ---- prologue: stage B(0), X(1); frags(0) straight from global X ----
#pragma unroll
    for (int q = 0; q < 8; ++q)
        stage16(Wt + srcoff[q], &Blds[0][(wave * 512 + q * 64) * 8]);
    stage4(xg + 4, &Xlds[1][0] + wave * 64);
#pragma unroll
    for (int m = 0; m < 4; ++m) {
        const float* xr = X + (size_t)(bm0 + wr * 64 + m * 16 + l15) * DIM;
        afr[m][0] = make_frag(xr[i0], halfSel, e0);
        afr[m][1] = make_frag(xr[i0 + 2], halfSel, e0);
    }
    __syncthreads();

    for (int t = 0; t < NSTEP; ++t) {
        const int cur = t & 1, nxt = cur ^ 1;
        // issue B(t+1) into other buffer
        if (t + 1 < NSTEP) {
#pragma unroll
            for (int q = 0; q < 8; ++q)
                stage16(Wt + srcoff[q] + (t + 1) * BK, &Blds[nxt][(wave * 512 + q * 64) * 8]);
        }
        // issue X(t+2) into Xlds[cur] (X(t) content dead after step t-1)
        if (t + 2 < NSTEP)
            stage4(xg + (t + 2) * 4, &Xlds[cur][0] + wave * 64);

        // compute frags(t+1) from Xlds[nxt] — independent of MFMA(t), interleaves
        bf16x8 afn[4][2];
        if (t + 1 < NSTEP) {
#pragma unroll
            for (int m = 0; m < 4; ++m) {
                int r = wr * 64 + m * 16 + l15;
                float x0 = Xlds[nxt][r * 4 + i0];
                float x1 = Xlds[nxt][r * 4 + i0 + 2];
                afn[m][0] = make_frag(x0, halfSel, e0);
                afn[m][1] = make_frag(x1, halfSel, e0);
            }
        }

        // MFMA on current B buffer, A from registers (64 MFMA / wave / step)
        const unsigned short* Bb = &Blds[cur][0];
#pragma unroll
        for (int kk = 0; kk < 2; ++kk) {
            const int up = (((kk * 4 + l4) ^ (l15 & 7)) * 8);
            bf16x8 bfr[8];
#pragma unroll
            for (int n = 0; n < 8; ++n)
                bfr[n] = *(bf16x8*)&Bb[(wc * 128 + n * 16 + l15) * BK + up];
#pragma unroll
            for (int m = 0; m < 4; ++m)
#pragma unroll
                for (int n = 0; n < 8; ++n)
                    acc[m][n] = __builtin_amdgcn_mfma_f32_16x16x32_bf16(afr[m][kk], bfr[n], acc[m][n], 0, 0, 0);
        }
        __syncthreads();
#pragma unroll
        for (int m = 0; m < 4; ++m) {
            afr[m][0] = afn[m][0];
            afr[m][1] = afn[m][1];
        }
    }

    // ---- epilogue: C/D layout col=lane&15, row=(lane>>4)*4+reg ----
#pragma unroll
    for (int m = 0; m < 4; ++m)
#pragma unroll
        for (int n = 0; n < 8; ++n)
#pragma unroll
            for (int j = 0; j < 4; ++j) {
                int row = bm0 + wr * 64 + m * 16 + l4 * 4 + j;
                int col = wc * 128 + n * 16 + l15;
                Y[(size_t)row * DIM + col] = acc[m][n][j];
            }
}

// ---------------- layer 4: in=512 -> out=1, one wave per row ----------------
__global__ void layer4(const float* __restrict__ X, const float* __restrict__ A4,
                       const float* __restrict__ B4, float* __restrict__ Y) {
    int wave = threadIdx.x >> 6, lane = threadIdx.x & 63;
    int b = blockIdx.x * 4 + wave;
    float acc = 0.f;
#pragma unroll
    for (int ii = 0; ii < 8; ++ii) {
        int i = lane + ii * 64;
        float xv = X[(size_t)b * DIM + i];
        float s1, c1;
        __sincosf(xv, &s1, &c1);
        const float* a = A4 + i * KF;
        const float* bb = B4 + i * KF;
        acc += bb[0];
        float sk = 0.f, ck = 1.f;
#pragma unroll
        for (int k = 1; k < KF; ++k) {
            float sn = sk * c1 + ck * s1;
            float cn = ck * c1 - sk * s1;
            sk = sn; ck = cn;
            acc += a[k] * sk + bb[k] * ck;
        }
    }
#pragma unroll
    for (int off = 32; off > 0; off >>= 1) acc += __shfl_down(acc, off, 64);
    if (lane == 0) Y[b] = acc;
}

extern "C" void kernel_launch(void* const* d_in, const int* in_sizes, int n_in,
                              void* d_out, int out_size, void* d_ws, size_t ws_size,
                              hipStream_t stream) {
    const float* x  = (const float*)d_in[0];
    const float* A0 = (const float*)d_in[1];
    const float* B0 = (const float*)d_in[2];
    const float* A1 = (const float*)d_in[3];
    const float* B1 = (const float*)d_in[4];
    const float* A2 = (const float*)d_in[5];
    const float* B2 = (const float*)d_in[6];
    const float* A3 = (const float*)d_in[7];
    const float* B3 = (const float*)d_in[8];
    const float* A4 = (const float*)d_in[9];
    const float* B4 = (const float*)d_in[10];
    float* out = (float*)d_out;

    char* ws = (char*)d_ws;
    const size_t actBytes = (size_t)NB * DIM * sizeof(float);   // 64 MB
    float* bufA = (float*)ws;
    float* bufB = (float*)(ws + actBytes);
    unsigned short* W1 = (unsigned short*)(ws + 2 * actBytes);
    unsigned short* W2 = W1 + (size_t)DIM * FEAT;
    unsigned short* W3 = W2 + (size_t)DIM * FEAT;

    pack_w<<<DIM * DIM / 256, 256, 0, stream>>>(A1, B1, W1);
    pack_w<<<DIM * DIM / 256, 256, 0, stream>>>(A2, B2, W2);
    pack_w<<<DIM * DIM / 256, 256, 0, stream>>>(A3, B3, W3);

    layer0<<<(NB * DIM) / 256, 256, 0, stream>>>(x, A0, B0, bufA);

    fkan_gemm<<<NB / BM, 512, 0, stream>>>(bufA, W1, bufB);
    fkan_gemm<<<NB / BM, 512, 0, stream>>>(bufB, W2, bufA);
    fkan_gemm<<<NB / BM, 512, 0, stream>>>(bufA, W3, bufB);

    layer4<<<NB / 4, 256, 0, stream>>>(bufB, A4, B4, out);
}

// Round 5
// 881.440 us; speedup vs baseline: 1.4878x; 1.4878x over previous
//
#include <hip/hip_runtime.h>
#include <hip/hip_bf16.h>
#include <math.h>

#define NB 32768
#define DIM 512
#define KF 8
#define FEAT 8192
#define BM 128
#define BK 64
#define NSTEP (FEAT / BK)   // 128

typedef __attribute__((ext_vector_type(8))) short bf16x8;
typedef __attribute__((ext_vector_type(4))) float f32x4;
typedef unsigned short ushort_t;
typedef unsigned int uint_t;

static __device__ __forceinline__ ushort_t f2bf_s(float f) {        // scalar bf16 (round-half-up)
    return (ushort_t)((__float_as_uint(f) + 0x8000u) >> 16);
}
static __device__ __forceinline__ float bf2f(ushort_t u) {
    return __uint_as_float(((uint_t)u) << 16);
}
// pack two floats -> one u32 holding 2 bf16 (round-half-up; sin/cos never NaN/Inf)
static __device__ __forceinline__ uint_t pk2(float a, float b) {
    return ((__float_as_uint(a) + 0x8000u) >> 16) | ((__float_as_uint(b) + 0x8000u) & 0xffff0000u);
}

static __device__ __forceinline__ void stage16(const ushort_t* g, ushort_t* l) {
    __builtin_amdgcn_global_load_lds((const __attribute__((address_space(1))) unsigned int*)g,
                                     (__attribute__((address_space(3))) unsigned int*)l, 16, 0, 0);
}

// ---------------- pack A,B (fp32 [512][512][8]) -> Wt bf16 [512][8192] ----------------
// Wt[o][i*16 + j] = A[o][i][j] (j<8), B[o][i][j-8] (j>=8)
__global__ void pack_w(const float* __restrict__ A, const float* __restrict__ B,
                       ushort_t* __restrict__ Wt) {
    int idx = blockIdx.x * 256 + threadIdx.x;
    int o = idx >> 9, i = idx & 511;
    const float* a = A + ((size_t)o * DIM + i) * KF;
    const float* b = B + ((size_t)o * DIM + i) * KF;
    bf16x8 v0, v1;
#pragma unroll
    for (int j = 0; j < 8; ++j) {
        v0[j] = (short)f2bf_s(a[j]);
        v1[j] = (short)f2bf_s(b[j]);
    }
    ushort_t* dst = Wt + (size_t)o * FEAT + i * 16;
    *(bf16x8*)dst = v0;
    *(bf16x8*)(dst + 8) = v1;
}

// ---------------- layer 0: in=1 -> out=512 (bf16 activations out) ----------------
__global__ void layer0(const float* __restrict__ x, const float* __restrict__ A0,
                       const float* __restrict__ B0, ushort_t* __restrict__ Y) {
    int gid = blockIdx.x * 256 + threadIdx.x;
    int b = gid >> 9, o = gid & 511;
    float xv = x[b];
    float s1, c1;
    __sincosf(xv, &s1, &c1);
    const float* a = A0 + o * KF;
    const float* bb = B0 + o * KF;
    float acc = bb[0];
    float sk = 0.f, ck = 1.f;
#pragma unroll
    for (int k = 1; k < KF; ++k) {
        float sn = sk * c1 + ck * s1;
        float cn = ck * c1 - sk * s1;
        sk = sn; ck = cn;
        acc += a[k] * sk + bb[k] * ck;
    }
    Y[gid] = f2bf_s(acc);
}

// ---------------- fused feature+GEMM: Y = F(X)[N][8192] * Wt[512][8192]^T, bf16 in/out ----------------
// Round-3 skeleton (A features in LDS, computed once per block) with the MFMA phase split:
// [all 24 ds_reads] [MFMA kk=0] | [features(t+1) on VALU pipe] | [MFMA kk=1] [barrier]
__global__ __launch_bounds__(512, 2) void fkan_gemm(const ushort_t* __restrict__ X,
                                                    const ushort_t* __restrict__ Wt,
                                                    ushort_t* __restrict__ Y) {
    __shared__ ushort_t Alds[2][BM * BK];   // 2 x 16 KB
    __shared__ ushort_t Blds[2][DIM * BK];  // 2 x 64 KB   (total 160 KB)
    const int tid = threadIdx.x;
    const int lane = tid & 63, wave = tid >> 6;
    const int wr = wave >> 2, wc = wave & 3;     // 2x4 wave grid, wave tile 64x128
    const int l15 = lane & 15, l4 = lane >> 4;
    const int bm0 = blockIdx.x * BM;

    // A staging: one (row, input) item per thread per step
    const int bl = tid >> 2, ii = tid & 3;
    const ushort_t* xp = X + (size_t)(bm0 + bl) * DIM + ii;
    const int au0 = (((ii * 2) ^ (bl & 7)) * 8) + bl * BK;
    const int au1 = (((ii * 2 + 1) ^ (bl & 7)) * 8) + bl * BK;

    // B staging: LDS slot u=(row,c) holds global unit (c ^ (row&7)) -> pre-swizzled src.
    int srcoff[8];
#pragma unroll
    for (int q = 0; q < 8; ++q) {
        int u = wave * 512 + q * 64 + lane;
        int row = u >> 3, c = u & 7;
        srcoff[q] = row * FEAT + ((c ^ (row & 7)) * 8);
    }

    // per-lane read offsets (ushort units), hoisted out of the loop
    int aoff[4], boff[8];
#pragma unroll
    for (int m = 0; m < 4; ++m) aoff[m] = (wr * 64 + m * 16 + l15) * BK;
#pragma unroll
    for (int n = 0; n < 8; ++n) boff[n] = (wc * 128 + n * 16 + l15) * BK;
    const int up0 = ((l4) ^ (l15 & 7)) * 8;
    const int up1 = ((4 + l4) ^ (l15 & 7)) * 8;

    f32x4 acc[4][8];
#pragma unroll
    for (int m = 0; m < 4; ++m)
#pragma unroll
        for (int n = 0; n < 8; ++n) acc[m][n] = (f32x4)0.f;

    // ---- prologue: stage B(0) + features(0) ----
#pragma unroll
    for (int q = 0; q < 8; ++q)
        stage16(Wt + srcoff[q], &Blds[0][(wave * 512 + q * 64) * 8]);
    {
        float xv0 = bf2f(xp[0]);
        float s1, c1;
        __sincosf(xv0, &s1, &c1);
        float s[KF], c[KF];
        s[0] = 0.f; c[0] = 1.f; s[1] = s1; c[1] = c1;
#pragma unroll
        for (int k = 2; k < KF; ++k) {
            s[k] = s[k - 1] * c1 + c[k - 1] * s1;
            c[k] = c[k - 1] * c1 - s[k - 1] * s1;
        }
        uint4 vs = { pk2(s[0], s[1]), pk2(s[2], s[3]), pk2(s[4], s[5]), pk2(s[6], s[7]) };
        uint4 vc = { pk2(c[0], c[1]), pk2(c[2], c[3]), pk2(c[4], c[5]), pk2(c[6], c[7]) };
        *(uint4*)&Alds[0][au0] = vs;
        *(uint4*)&Alds[0][au1] = vc;
    }
    float xv = bf2f(xp[4]);    // x for features(1)
    __syncthreads();

    for (int t = 0; t < NSTEP; ++t) {
        const int cur = t & 1, nxt = cur ^ 1;
        // ---- issue B(t+1) stages ----
        if (t + 1 < NSTEP) {
#pragma unroll
            for (int q = 0; q < 8; ++q)
                stage16(Wt + srcoff[q] + (t + 1) * BK, &Blds[nxt][(wave * 512 + q * 64) * 8]);
        }
        // ---- all 24 frag reads (kk=0 group first so MFMA0 waits only lgkmcnt(12)) ----
        const ushort_t* Ab = &Alds[cur][0];
        const ushort_t* Bb = &Blds[cur][0];
        bf16x8 af0[4], bf0[8], af1[4], bf1[8];
#pragma unroll
        for (int m = 0; m < 4; ++m) af0[m] = *(const bf16x8*)&Ab[aoff[m] + up0];
#pragma unroll
        for (int n = 0; n < 8; ++n) bf0[n] = *(const bf16x8*)&Bb[boff[n] + up0];
#pragma unroll
        for (int m = 0; m < 4; ++m) af1[m] = *(const bf16x8*)&Ab[aoff[m] + up1];
#pragma unroll
        for (int n = 0; n < 8; ++n) bf1[n] = *(const bf16x8*)&Bb[boff[n] + up1];

        // ---- MFMA kk=0 (32) ----
        __builtin_amdgcn_s_setprio(1);
#pragma unroll
        for (int m = 0; m < 4; ++m)
#pragma unroll
            for (int n = 0; n < 8; ++n)
                acc[m][n] = __builtin_amdgcn_mfma_f32_16x16x32_bf16(af0[m], bf0[n], acc[m][n], 0, 0, 0);
        __builtin_amdgcn_s_setprio(0);
        __builtin_amdgcn_sched_barrier(0);

        // ---- features(t+1) on VALU pipe (overlaps MFMA0 drain) ----
        if (t + 1 < NSTEP) {
            float s1, c1;
            __sincosf(xv, &s1, &c1);
            float s[KF], c[KF];
            s[0] = 0.f; c[0] = 1.f; s[1] = s1; c[1] = c1;
#pragma unroll
            for (int k = 2; k < KF; ++k) {
                s[k] = s[k - 1] * c1 + c[k - 1] * s1;
                c[k] = c[k - 1] * c1 - s[k - 1] * s1;
            }
            uint4 vs = { pk2(s[0], s[1]), pk2(s[2], s[3]), pk2(s[4], s[5]), pk2(s[6], s[7]) };
            uint4 vc = { pk2(c[0], c[1]), pk2(c[2], c[3]), pk2(c[4], c[5]), pk2(c[6], c[7]) };
            *(uint4*)&Alds[nxt][au0] = vs;
            *(uint4*)&Alds[nxt][au1] = vc;
            if (t + 2 < NSTEP) xv = bf2f(xp[(t + 2) * 4]);
        }
        __builtin_amdgcn_sched_barrier(0);

        // ---- MFMA kk=1 (32) ----
        __builtin_amdgcn_s_setprio(1);
#pragma unroll
        for (int m = 0; m < 4; ++m)
#pragma unroll
            for (int n = 0; n < 8; ++n)
                acc[m][n] = __builtin_amdgcn_mfma_f32_16x16x32_bf16(af1[m], bf1[n], acc[m][n], 0, 0, 0);
        __builtin_amdgcn_s_setprio(0);

        __syncthreads();
    }

    // ---- epilogue: C/D layout col=lane&15, row=(lane>>4)*4+reg; bf16 store ----
#pragma unroll
    for (int m = 0; m < 4; ++m)
#pragma unroll
        for (int n = 0; n < 8; ++n)
#pragma unroll
            for (int j = 0; j < 4; ++j) {
                int row = bm0 + wr * 64 + m * 16 + l4 * 4 + j;
                int col = wc * 128 + n * 16 + l15;
                Y[(size_t)row * DIM + col] = f2bf_s(acc[m][n][j]);
            }
}

// ---------------- layer 4: in=512 -> out=1, one wave per row (bf16 X) ----------------
__global__ void layer4(const ushort_t* __restrict__ X, const float* __restrict__ A4,
                       const float* __restrict__ B4, float* __restrict__ Y) {
    int wave = threadIdx.x >> 6, lane = threadIdx.x & 63;
    int b = blockIdx.x * 4 + wave;
    float acc = 0.f;
#pragma unroll
    for (int ii = 0; ii < 8; ++ii) {
        int i = lane + ii * 64;
        float xv = bf2f(X[(size_t)b * DIM + i]);
        float s1, c1;
        __sincosf(xv, &s1, &c1);
        const float* a = A4 + i * KF;
        const float* bb = B4 + i * KF;
        acc += bb[0];
        float sk = 0.f, ck = 1.f;
#pragma unroll
        for (int k = 1; k < KF; ++k) {
            float sn = sk * c1 + ck * s1;
            float cn = ck * c1 - sk * s1;
            sk = sn; ck = cn;
            acc += a[k] * sk + bb[k] * ck;
        }
    }
#pragma unroll
    for (int off = 32; off > 0; off >>= 1) acc += __shfl_down(acc, off, 64);
    if (lane == 0) Y[b] = acc;
}

extern "C" void kernel_launch(void* const* d_in, const int* in_sizes, int n_in,
                              void* d_out, int out_size, void* d_ws, size_t ws_size,
                              hipStream_t stream) {
    const float* x  = (const float*)d_in[0];
    const float* A0 = (const float*)d_in[1];
    const float* B0 = (const float*)d_in[2];
    const float* A1 = (const float*)d_in[3];
    const float* B1 = (const float*)d_in[4];
    const float* A2 = (const float*)d_in[5];
    const float* B2 = (const float*)d_in[6];
    const float* A3 = (const float*)d_in[7];
    const float* B3 = (const float*)d_in[8];
    const float* A4 = (const float*)d_in[9];
    const float* B4 = (const float*)d_in[10];
    float* out = (float*)d_out;

    char* ws = (char*)d_ws;
    const size_t actBytes = (size_t)NB * DIM * sizeof(ushort_t);  // 32 MB (bf16 activations)
    ushort_t* bufA = (ushort_t*)ws;
    ushort_t* bufB = (ushort_t*)(ws + actBytes);
    ushort_t* W1 = (ushort_t*)(ws + 2 * actBytes);
    ushort_t* W2 = W1 + (size_t)DIM * FEAT;
    ushort_t* W3 = W2 + (size_t)DIM * FEAT;

    pack_w<<<DIM * DIM / 256, 256, 0, stream>>>(A1, B1, W1);
    pack_w<<<DIM * DIM / 256, 256, 0, stream>>>(A2, B2, W2);
    pack_w<<<DIM * DIM / 256, 256, 0, stream>>>(A3, B3, W3);

    layer0<<<(NB * DIM) / 256, 256, 0, stream>>>(x, A0, B0, bufA);

    fkan_gemm<<<NB / BM, 512, 0, stream>>>(bufA, W1, bufB);
    fkan_gemm<<<NB / BM, 512, 0, stream>>>(bufB, W2, bufA);
    fkan_gemm<<<NB / BM, 512, 0, stream>>>(bufA, W3, bufB);

    layer4<<<NB / 4, 256, 0, stream>>>(bufB, A4, B4, out);
}